// Round 1
// baseline (640.377 us; speedup 1.0000x reference)
//
#include <hip/hip_runtime.h>
#include <hip/hip_bf16.h>
#include <math.h>

// Problem constants
#define SS    2048   // S
#define BB    64     // B
#define HH    1024   // H == DH
#define DD    64     // half window
#define WW    129    // window size
#define ROWSZ 65536  // B*H floats per enc row (S-major)

// ---------------------------------------------------------------------------
// K1: partials[b][blk] = sum_{h in blk*8..blk*8+7} vp_w[h] * tanh(hidden[b]·Wp_w[h] + Wp_b[h])
// grid 128 blocks x 256 threads. Each block: 8 h rows staged in LDS, 2 b per thread.
// ---------------------------------------------------------------------------
__global__ __launch_bounds__(256) void lpa_k1(
    const float* __restrict__ hidden, const float* __restrict__ Wp_w,
    const float* __restrict__ Wp_b,   const float* __restrict__ vp_w,
    float* __restrict__ partials)
{
    __shared__ float wlds[8 * 1028];  // +4 pad per row -> conflict-free across hj
    const int tid = threadIdx.x;
    const int blk = blockIdx.x;
    const int h0  = blk * 8;

#pragma unroll
    for (int r = 0; r < 8; ++r) {
        float4 v = ((const float4*)(Wp_w + (size_t)(h0 + r) * HH))[tid];
        *(float4*)(&wlds[r * 1028 + tid * 4]) = v;
    }
    __syncthreads();

    const int hj = tid & 7;     // which h row of the 8
    const int bg = tid >> 3;    // 0..31
    const int b0 = bg * 2, b1 = b0 + 1;

    const float4* hid0 = (const float4*)(hidden + (size_t)b0 * HH);
    const float4* hid1 = (const float4*)(hidden + (size_t)b1 * HH);
    const float4* wr   = (const float4*)(&wlds[hj * 1028]);

    float4 A0 = {0.f, 0.f, 0.f, 0.f};
    float4 A1 = {0.f, 0.f, 0.f, 0.f};
#pragma unroll 8
    for (int i = 0; i < 256; ++i) {
        float4 wv = wr[i];
        float4 a  = hid0[i];
        float4 c  = hid1[i];
        A0.x = fmaf(a.x, wv.x, A0.x); A0.y = fmaf(a.y, wv.y, A0.y);
        A0.z = fmaf(a.z, wv.z, A0.z); A0.w = fmaf(a.w, wv.w, A0.w);
        A1.x = fmaf(c.x, wv.x, A1.x); A1.y = fmaf(c.y, wv.y, A1.y);
        A1.z = fmaf(c.z, wv.z, A1.z); A1.w = fmaf(c.w, wv.w, A1.w);
    }
    float d0 = (A0.x + A0.y) + (A0.z + A0.w);
    float d1 = (A1.x + A1.y) + (A1.z + A1.w);

    const int h = h0 + hj;
    float t0 = tanhf(d0 + Wp_b[h]) * vp_w[h];
    float t1 = tanhf(d1 + Wp_b[h]) * vp_w[h];

    // reduce across the 8 hj lanes (consecutive lanes share bg)
#pragma unroll
    for (int m = 1; m < 8; m <<= 1) {
        t0 += __shfl_xor(t0, m, 64);
        t1 += __shfl_xor(t1, m, 64);
    }
    if (hj == 0) {
        partials[b0 * 128 + blk] = t0;
        partials[b1 * 128 + blk] = t1;
    }
}

// ---------------------------------------------------------------------------
// K2: p[b] = S*sigmoid(sum(partials)+vp_b); scores[b][w] = hidden[b]·enc[row_w,b,:]
// grid (33, 64) x 256 threads; each wave handles one window position w.
// ---------------------------------------------------------------------------
__global__ __launch_bounds__(256) void lpa_k2(
    const float* __restrict__ hidden, const float* __restrict__ enc,
    const float* __restrict__ partials, const float* __restrict__ vp_b,
    float* __restrict__ scores, float* __restrict__ p_ws)
{
    const int b   = blockIdx.y;
    const int wc  = blockIdx.x;
    const int tid = threadIdx.x;
    __shared__ float pSh;

    if (tid < 64) {
        float v = partials[b * 128 + tid] + partials[b * 128 + 64 + tid];
#pragma unroll
        for (int m = 32; m > 0; m >>= 1) v += __shfl_xor(v, m, 64);
        if (tid == 0) {
            float pre = v + vp_b[0];
            float p = (float)SS / (1.f + expf(-pre));
            pSh = p;
            if (wc == 0) p_ws[b] = p;
        }
    }
    __syncthreads();

    const float p = pSh;
    const int center = (int)rintf(p);   // banker's rounding, matches jnp.round
    const int wave = tid >> 6, lane = tid & 63;
    const int w = wc * 4 + wave;
    if (w >= WW) return;

    const int row = center + w - DD;
    float sc = 0.f;
    if (row >= 0 && row < SS) {
        const float4* ev = (const float4*)(enc + (size_t)row * ROWSZ + (size_t)b * HH);
        const float4* hv = (const float4*)(hidden + (size_t)b * HH);
        float4 A = {0.f, 0.f, 0.f, 0.f};
#pragma unroll
        for (int it = 0; it < 4; ++it) {
            float4 e4 = ev[lane + it * 64];
            float4 h4 = hv[lane + it * 64];
            A.x = fmaf(e4.x, h4.x, A.x);
            A.y = fmaf(e4.y, h4.y, A.y);
            A.z = fmaf(e4.z, h4.z, A.z);
            A.w = fmaf(e4.w, h4.w, A.w);
        }
        float s = (A.x + A.y) + (A.z + A.w);
#pragma unroll
        for (int m = 32; m > 0; m >>= 1) s += __shfl_xor(s, m, 64);
        sc = s;
    }
    if (lane == 0) scores[b * WW + w] = sc;
}

// ---------------------------------------------------------------------------
// K3: softmax over w + gaussian scale -> attn_scaled out; context accumulation.
// grid (4, 64) x 256 threads; h = hc*256 + tid.
// ---------------------------------------------------------------------------
__global__ __launch_bounds__(256) void lpa_k3(
    const float* __restrict__ enc, const float* __restrict__ scores,
    const float* __restrict__ p_ws, float* __restrict__ out)
{
    const int b   = blockIdx.y;
    const int hc  = blockIdx.x;
    const int tid = threadIdx.x;
    __shared__ float red[256];
    __shared__ float aSh[WW];

    const float p = p_ws[b];
    const int center = (int)rintf(p);

    float sv = (tid < WW) ? scores[b * WW + tid] : -INFINITY;
    red[tid] = sv;
    __syncthreads();
#pragma unroll
    for (int s = 128; s > 0; s >>= 1) {
        if (tid < s) red[tid] = fmaxf(red[tid], red[tid + s]);
        __syncthreads();
    }
    const float mx = red[0];
    __syncthreads();

    float e = (tid < WW) ? expf(sv - mx) : 0.f;
    red[tid] = e;
    __syncthreads();
#pragma unroll
    for (int s = 128; s > 0; s >>= 1) {
        if (tid < s) red[tid] += red[tid + s];
        __syncthreads();
    }
    const float inv = 1.f / red[0];

    if (tid < WW) {
        float dlt = (float)(center + tid - DD) - p;      // window_index - p
        float g = expf(dlt * dlt * (-1.f / 2048.f));     // 2*(D/2)^2 = 2048
        float av = e * inv * g;
        aSh[tid] = av;
        if (hc == 0) out[b * WW + tid] = av;             // attn_scaled output
    }
    __syncthreads();

    const int h = hc * 256 + tid;
    const float* encb = enc + (size_t)b * HH + h;

    // valid w range: row = center + w - D in [0, S)
    const int lo = (center >= DD) ? 0 : (DD - center);
    const int hi = (2112 - center < WW) ? (2112 - center) : WW;  // 2112 = S + D

    float acc0 = 0.f, acc1 = 0.f, acc2 = 0.f, acc3 = 0.f;
    for (int w = lo; w < hi; w += 4) {
        const size_t base = (size_t)(center + w - DD) * ROWSZ;
        acc0 = fmaf(aSh[w], encb[base], acc0);
        if (w + 1 < hi) acc1 = fmaf(aSh[w + 1], encb[base + ROWSZ], acc1);
        if (w + 2 < hi) acc2 = fmaf(aSh[w + 2], encb[base + 2 * (size_t)ROWSZ], acc2);
        if (w + 3 < hi) acc3 = fmaf(aSh[w + 3], encb[base + 3 * (size_t)ROWSZ], acc3);
    }
    out[BB * WW + b * HH + h] = (acc0 + acc1) + (acc2 + acc3);
}

// ---------------------------------------------------------------------------
extern "C" void kernel_launch(void* const* d_in, const int* in_sizes, int n_in,
                              void* d_out, int out_size, void* d_ws, size_t ws_size,
                              hipStream_t stream)
{
    // inputs: 0=t (unused), 1=hidden, 2=encoder_outputs, 3=Wp_w, 4=Wp_b, 5=vp_w, 6=vp_b
    const float* hidden = (const float*)d_in[1];
    const float* enc    = (const float*)d_in[2];
    const float* Wp_w   = (const float*)d_in[3];
    const float* Wp_b   = (const float*)d_in[4];
    const float* vp_w   = (const float*)d_in[5];
    const float* vp_b   = (const float*)d_in[6];
    float* out = (float*)d_out;

    float* ws       = (float*)d_ws;
    float* partials = ws;                   // 64*128 = 8192 floats
    float* scores   = ws + 8192;            // 64*129 = 8256 floats
    float* p_ws     = ws + 8192 + 8256;     // 64 floats

    lpa_k1<<<128, 256, 0, stream>>>(hidden, Wp_w, Wp_b, vp_w, partials);
    lpa_k2<<<dim3(33, 64), 256, 0, stream>>>(hidden, enc, partials, vp_b, scores, p_ws);
    lpa_k3<<<dim3(4, 64), 256, 0, stream>>>(enc, scores, p_ws, out);
}

// Round 2
// 622.681 us; speedup vs baseline: 1.0284x; 1.0284x over previous
//
#include <hip/hip_runtime.h>
#include <hip/hip_bf16.h>
#include <math.h>

// Problem constants
#define SS    2048   // S
#define BB    64     // B
#define HH    1024   // H == DH
#define DD    64     // half window
#define WW    129    // window size
#define ROWSZ 65536  // B*H floats per enc row (S-major)

// ---------------------------------------------------------------------------
// K1: partials[b][blk] = sum_{h in blk*8..blk*8+7} vp_w[h] * tanh(hidden[b]·Wp_w[h] + Wp_b[h])
// grid 128 blocks x 256 threads. Each block: 8 h rows staged in LDS, 2 b per thread.
// Wave lane groups (8 lanes, same bg) read identical hidden float4 -> coalescer
// broadcast; unique hidden traffic per block = 256 KB (L2-resident).
// ---------------------------------------------------------------------------
__global__ __launch_bounds__(256) void lpa_k1(
    const float* __restrict__ hidden, const float* __restrict__ Wp_w,
    const float* __restrict__ Wp_b,   const float* __restrict__ vp_w,
    float* __restrict__ partials)
{
    __shared__ float wlds[8 * 1028];  // +4 pad per row -> conflict-free across hj
    const int tid = threadIdx.x;
    const int blk = blockIdx.x;
    const int h0  = blk * 8;

#pragma unroll
    for (int r = 0; r < 8; ++r) {
        float4 v = ((const float4*)(Wp_w + (size_t)(h0 + r) * HH))[tid];
        *(float4*)(&wlds[r * 1028 + tid * 4]) = v;
    }
    __syncthreads();

    const int hj = tid & 7;     // which h row of the 8
    const int bg = tid >> 3;    // 0..31
    const int b0 = bg * 2, b1 = b0 + 1;

    const float4* hid0 = (const float4*)(hidden + (size_t)b0 * HH);
    const float4* hid1 = (const float4*)(hidden + (size_t)b1 * HH);
    const float4* wr   = (const float4*)(&wlds[hj * 1028]);

    float4 A0 = {0.f, 0.f, 0.f, 0.f};
    float4 A1 = {0.f, 0.f, 0.f, 0.f};
#pragma unroll 8
    for (int i = 0; i < 256; ++i) {
        float4 wv = wr[i];
        float4 a  = hid0[i];
        float4 c  = hid1[i];
        A0.x = fmaf(a.x, wv.x, A0.x); A0.y = fmaf(a.y, wv.y, A0.y);
        A0.z = fmaf(a.z, wv.z, A0.z); A0.w = fmaf(a.w, wv.w, A0.w);
        A1.x = fmaf(c.x, wv.x, A1.x); A1.y = fmaf(c.y, wv.y, A1.y);
        A1.z = fmaf(c.z, wv.z, A1.z); A1.w = fmaf(c.w, wv.w, A1.w);
    }
    float d0 = (A0.x + A0.y) + (A0.z + A0.w);
    float d1 = (A1.x + A1.y) + (A1.z + A1.w);

    const int h = h0 + hj;
    float t0 = tanhf(d0 + Wp_b[h]) * vp_w[h];
    float t1 = tanhf(d1 + Wp_b[h]) * vp_w[h];

    // reduce across the 8 hj lanes (consecutive lanes share bg)
#pragma unroll
    for (int m = 1; m < 8; m <<= 1) {
        t0 += __shfl_xor(t0, m, 64);
        t1 += __shfl_xor(t1, m, 64);
    }
    if (hj == 0) {
        partials[b0 * 128 + blk] = t0;
        partials[b1 * 128 + blk] = t1;
    }
}

// ---------------------------------------------------------------------------
// K2: p[b] = S*sigmoid(sum(partials)+vp_b); scores[b][w] = hidden[b]·enc[row_w,b,:]
// grid (17, 64) x 512 threads; 8 waves/block, each wave one window position w.
// ---------------------------------------------------------------------------
__global__ __launch_bounds__(512) void lpa_k2(
    const float* __restrict__ hidden, const float* __restrict__ enc,
    const float* __restrict__ partials, const float* __restrict__ vp_b,
    float* __restrict__ scores, float* __restrict__ p_ws)
{
    const int b   = blockIdx.y;
    const int wc  = blockIdx.x;
    const int tid = threadIdx.x;
    __shared__ float pSh;

    if (tid < 64) {
        float v = partials[b * 128 + tid] + partials[b * 128 + 64 + tid];
#pragma unroll
        for (int m = 32; m > 0; m >>= 1) v += __shfl_xor(v, m, 64);
        if (tid == 0) {
            float pre = v + vp_b[0];
            float p = (float)SS / (1.f + expf(-pre));
            pSh = p;
            if (wc == 0) p_ws[b] = p;
        }
    }
    __syncthreads();

    const float p = pSh;
    const int center = (int)rintf(p);   // banker's rounding, matches jnp.round
    const int wave = tid >> 6, lane = tid & 63;
    const int w = wc * 8 + wave;
    if (w >= WW) return;

    const int row = center + w - DD;
    float sc = 0.f;
    if (row >= 0 && row < SS) {
        const float4* ev = (const float4*)(enc + (size_t)row * ROWSZ + (size_t)b * HH);
        const float4* hv = (const float4*)(hidden + (size_t)b * HH);
        float4 A = {0.f, 0.f, 0.f, 0.f};
#pragma unroll
        for (int it = 0; it < 4; ++it) {
            float4 e4 = ev[lane + it * 64];
            float4 h4 = hv[lane + it * 64];
            A.x = fmaf(e4.x, h4.x, A.x);
            A.y = fmaf(e4.y, h4.y, A.y);
            A.z = fmaf(e4.z, h4.z, A.z);
            A.w = fmaf(e4.w, h4.w, A.w);
        }
        float s = (A.x + A.y) + (A.z + A.w);
#pragma unroll
        for (int m = 32; m > 0; m >>= 1) s += __shfl_xor(s, m, 64);
        sc = s;
    }
    if (lane == 0) scores[b * WW + w] = sc;
}

// ---------------------------------------------------------------------------
// K3: softmax over w + gaussian scale -> attn_scaled out; context accumulation.
// grid (4, 64) x 256 threads; h = hc*256 + tid. enc rows are L3-resident (K2
// just touched them). 4 independent FMA chains hide L3 latency.
// ---------------------------------------------------------------------------
__global__ __launch_bounds__(256) void lpa_k3(
    const float* __restrict__ enc, const float* __restrict__ scores,
    const float* __restrict__ p_ws, float* __restrict__ out)
{
    const int b   = blockIdx.y;
    const int hc  = blockIdx.x;
    const int tid = threadIdx.x;
    __shared__ float red[256];
    __shared__ float aSh[WW];

    const float p = p_ws[b];
    const int center = (int)rintf(p);

    float sv = (tid < WW) ? scores[b * WW + tid] : -INFINITY;
    red[tid] = sv;
    __syncthreads();
#pragma unroll
    for (int s = 128; s > 0; s >>= 1) {
        if (tid < s) red[tid] = fmaxf(red[tid], red[tid + s]);
        __syncthreads();
    }
    const float mx = red[0];
    __syncthreads();

    float e = (tid < WW) ? expf(sv - mx) : 0.f;
    red[tid] = e;
    __syncthreads();
#pragma unroll
    for (int s = 128; s > 0; s >>= 1) {
        if (tid < s) red[tid] += red[tid + s];
        __syncthreads();
    }
    const float inv = 1.f / red[0];

    if (tid < WW) {
        float dlt = (float)(center + tid - DD) - p;      // window_index - p
        float g = expf(dlt * dlt * (-1.f / 2048.f));     // 2*(D/2)^2 = 2048
        float av = e * inv * g;
        aSh[tid] = av;
        if (hc == 0) out[b * WW + tid] = av;             // attn_scaled output
    }
    __syncthreads();

    const int h = hc * 256 + tid;
    const float* encb = enc + (size_t)b * HH + h;

    // valid w range: row = center + w - D in [0, S)
    const int lo = (center >= DD) ? 0 : (DD - center);
    const int hi = (2112 - center < WW) ? (2112 - center) : WW;  // 2112 = S + D

    float acc0 = 0.f, acc1 = 0.f, acc2 = 0.f, acc3 = 0.f;
    int w = lo;
    for (; w + 3 < hi; w += 4) {
        const float* base = encb + (size_t)(center + w - DD) * ROWSZ;
        acc0 = fmaf(aSh[w],     base[0],                  acc0);
        acc1 = fmaf(aSh[w + 1], base[ROWSZ],              acc1);
        acc2 = fmaf(aSh[w + 2], base[2 * (size_t)ROWSZ],  acc2);
        acc3 = fmaf(aSh[w + 3], base[3 * (size_t)ROWSZ],  acc3);
    }
    for (; w < hi; ++w)
        acc0 = fmaf(aSh[w], encb[(size_t)(center + w - DD) * ROWSZ], acc0);
    out[BB * WW + b * HH + h] = (acc0 + acc1) + (acc2 + acc3);
}

// ---------------------------------------------------------------------------
extern "C" void kernel_launch(void* const* d_in, const int* in_sizes, int n_in,
                              void* d_out, int out_size, void* d_ws, size_t ws_size,
                              hipStream_t stream)
{
    // inputs: 0=t (unused), 1=hidden, 2=encoder_outputs, 3=Wp_w, 4=Wp_b, 5=vp_w, 6=vp_b
    const float* hidden = (const float*)d_in[1];
    const float* enc    = (const float*)d_in[2];
    const float* Wp_w   = (const float*)d_in[3];
    const float* Wp_b   = (const float*)d_in[4];
    const float* vp_w   = (const float*)d_in[5];
    const float* vp_b   = (const float*)d_in[6];
    float* out = (float*)d_out;

    float* ws       = (float*)d_ws;
    float* partials = ws;                   // 64*128 = 8192 floats
    float* scores   = ws + 8192;            // 64*129 = 8256 floats
    float* p_ws     = ws + 8192 + 8256;     // 64 floats

    lpa_k1<<<128, 256, 0, stream>>>(hidden, Wp_w, Wp_b, vp_w, partials);
    lpa_k2<<<dim3(17, 64), 512, 0, stream>>>(hidden, enc, partials, vp_b, scores, p_ws);
    lpa_k3<<<dim3(4, 64), 256, 0, stream>>>(enc, scores, p_ws, out);
}